// Round 5
// baseline (176.055 us; speedup 1.0000x reference)
//
#include <hip/hip_runtime.h>
#include <cstdint>

#define QSCALE 0.40824829046386301636f  // 6^-0.5

// ============================================================================
// qkv_first: x[N][24] -> q[4][N][6] (pre-scaled), kv[4][N][12] ({k6,v6})
// ============================================================================
__global__ __launch_bounds__(256) void qkv_first(
    const float* __restrict__ x, const float* __restrict__ w,
    const float* __restrict__ b, float* __restrict__ q,
    float* __restrict__ kv, int npx)
{
  __shared__ __align__(16) float swT[72 * 24];  // transposed: swT[j][c]
  __shared__ float sb[72];
  for (int i = threadIdx.x; i < 1728; i += 256) swT[(i % 72) * 24 + i / 72] = w[i];
  if (threadIdx.x < 72) sb[threadIdx.x] = b[threadIdx.x];
  __syncthreads();
  const int t = blockIdx.x * 256 + threadIdx.x;
  const int p = t >> 2, jg = t & 3;
  if (p >= npx) return;
  float xr[24];
  const float4* xp = (const float4*)(x + (size_t)p * 24);
#pragma unroll
  for (int i = 0; i < 6; ++i) {
    const float4 f = xp[i];
    xr[4*i] = f.x; xr[4*i+1] = f.y; xr[4*i+2] = f.z; xr[4*i+3] = f.w;
  }
#pragma unroll
  for (int jj = 0; jj < 18; ++jj) {
    const int j = jg * 18 + jj;
    const float* wr = &swT[j * 24];
    float acc = sb[j];
#pragma unroll
    for (int c = 0; c < 24; ++c) acc += xr[c] * wr[c];
    if (j < 24)      q[((size_t)(j / 6) * npx + p) * 6 + j % 6] = acc * QSCALE;
    else if (j < 48) { const int u = j - 24; kv[((size_t)(u / 6) * npx + p) * 12 + u % 6] = acc; }
    else             { const int u = j - 48; kv[((size_t)(u / 6) * npx + p) * 12 + 6 + u % 6] = acc; }
  }
}

// ============================================================================
// attn5: win=5 attention, one head per block.  Block = 8x8 queries, 128 thr =
// (q 64) x (row-slice 2).  Whole per-head window staged once -> one barrier.
// ============================================================================
__global__ __launch_bounds__(128) void attn5(
    const float* __restrict__ q, const float* __restrict__ kv,
    float* __restrict__ att, int H, int W)
{
  __shared__ __align__(16) float skv[12 * 12 * 12];
  const int tid = threadIdx.x;
  const int h0 = blockIdx.y * 8, w0 = blockIdx.x * 8, hd = blockIdx.z;
  const int N = H * W;
  const int rlo = min(max(h0 - 2, 0), H - 5);
  const int nr  = min(max(h0 + 5, 0), H - 5) + 4 - rlo + 1;   // <= 12
  const int clo = min(max(w0 - 2, 0), W - 5);
  const int nc  = min(max(w0 + 5, 0), W - 5) + 4 - clo + 1;   // <= 12
  const float* kvh = kv + (size_t)hd * N * 12;
  const int ncc = nc * 3;
  for (int i = tid; i < nr * ncc; i += 128) {
    const int r = i / ncc, c4 = i - r * ncc;
    const float4 v = ((const float4*)(kvh + ((size_t)(rlo + r) * W + clo) * 12))[c4];
    ((float4*)skv)[r * 36 + c4] = v;   // LDS row stride = 12 px * 12 f
  }
  __syncthreads();

  const int ql = tid >> 1, sr = tid & 1;
  const int qh = h0 + (ql >> 3), qw = w0 + (ql & 7);
  const float* qp = q + ((size_t)hd * N + (size_t)qh * W + qw) * 6;
  const float q0 = qp[0], q1 = qp[1], q2 = qp[2], q3 = qp[3], q4 = qp[4], q5 = qp[5];
  const int shq = min(max(qh - 2, 0), H - 5) - rlo;
  const int swq = min(max(qw - 2, 0), W - 5) - clo;

  float m = -1e30f, l = 0.f, a0 = 0, a1 = 0, a2 = 0, a3 = 0, a4 = 0, a5 = 0;
  for (int rr = sr; rr < 5; rr += 2) {
    const float* rowp = skv + ((shq + rr) * 12 + swq) * 12;
#pragma unroll
    for (int cc = 0; cc < 5; ++cc) {
      const float* p = rowp + cc * 12;
      const float4 A = *(const float4*)p;
      const float4 B = *(const float4*)(p + 4);
      const float4 C = *(const float4*)(p + 8);
      const float s = q0*A.x + q1*A.y + q2*A.z + q3*A.w + q4*B.x + q5*B.y;
      float d = s - m;
      if (d > 8.0f) {
        const float r2 = __expf(-d);
        l *= r2; a0 *= r2; a1 *= r2; a2 *= r2; a3 *= r2; a4 *= r2; a5 *= r2;
        m = s; d = 0.f;
      }
      const float e = __expf(d);
      l += e;
      a0 += e*B.z; a1 += e*B.w; a2 += e*C.x;
      a3 += e*C.y; a4 += e*C.z; a5 += e*C.w;
    }
  }
  {  // merge the sr pair (adjacent lanes)
    const float om = __shfl_xor(m, 1), ol = __shfl_xor(l, 1);
    const float o0 = __shfl_xor(a0, 1), o1 = __shfl_xor(a1, 1), o2 = __shfl_xor(a2, 1);
    const float o3 = __shfl_xor(a3, 1), o4 = __shfl_xor(a4, 1), o5 = __shfl_xor(a5, 1);
    const float nm = fmaxf(m, om);
    const float f1 = __expf(m - nm), f2 = __expf(om - nm);
    l = l*f1 + ol*f2;
    a0 = a0*f1 + o0*f2; a1 = a1*f1 + o1*f2; a2 = a2*f1 + o2*f2;
    a3 = a3*f1 + o3*f2; a4 = a4*f1 + o4*f2; a5 = a5*f1 + o5*f2;
  }
  if (sr == 0) {
    const float inv = 1.0f / l;
    float* ap = att + ((size_t)qh * W + qw) * 24 + hd * 6;
    ((float2*)ap)[0] = make_float2(a0*inv, a1*inv);
    ((float2*)ap)[1] = make_float2(a2*inv, a3*inv);
    ((float2*)ap)[2] = make_float2(a4*inv, a5*inv);
  }
}

// ============================================================================
// attn25: win=25 attention, one head per block.  Block = 4x8 queries, 256 thr
// = qw(8) x row-slice(8) x col-slice(4); tid = qw*32 + sr*4 + sc.
// Each thread holds 4 QUERY ROWS in registers and applies each staged key to
// all row-valid queries (validity block-uniform) -> 4x less LDS traffic.
// LDS row stride 388 f (== 4 mod 32 banks) -> 8 sr lanes hit 8 distinct
// bank-quads -> conflict-free b128.  Merge 32 slices via shfl_xor butterfly.
// ============================================================================
__global__ __launch_bounds__(256) void attn25(
    const float* __restrict__ q, const float* __restrict__ kv,
    float* __restrict__ att)
{
  constexpr int H = 64, W = 88, N = H * W;
  constexpr int RS = 388;                       // LDS floats per key-row
  __shared__ __align__(16) float skv[28 * RS];  // 43.5 KB
  const int tid = threadIdx.x;
  const int h0 = blockIdx.y * 4, w0 = blockIdx.x * 8, hd = blockIdx.z;
  const int rlo = min(max(h0 - 12, 0), H - 25);
  const int nr  = min(max(h0 + 3 - 12, 0), H - 25) + 24 - rlo + 1;  // <= 28
  const int clo = min(max(w0 - 12, 0), W - 25);
  const int nc  = min(max(w0 + 7 - 12, 0), W - 25) + 24 - clo + 1;  // <= 32
  const float* kvh = kv + (size_t)hd * N * 12;
  const int ncc = nc * 3;
  for (int i = tid; i < nr * ncc; i += 256) {
    const int r = i / ncc, c4 = i - r * ncc;
    const float4 v = ((const float4*)(kvh + ((size_t)(rlo + r) * W + clo) * 12))[c4];
    ((float4*)skv)[r * (RS / 4) + c4] = v;
  }
  __syncthreads();

  const int qw_ = tid >> 5, slice = tid & 31, sr = slice >> 2, sc = slice & 3;
  const int qw = w0 + qw_;
  const int swq = min(max(qw - 12, 0), W - 25) - clo;   // 0..7

  float qv[4][6];
  int srel[4];
#pragma unroll
  for (int qi = 0; qi < 4; ++qi) {
    const float* qp = q + ((size_t)hd * N + (size_t)(h0 + qi) * W + qw) * 6;
#pragma unroll
    for (int d = 0; d < 6; ++d) qv[qi][d] = qp[d];
    srel[qi] = min(max(h0 + qi - 12, 0), H - 25) - rlo;  // block-uniform, 0..3
  }

  float m_[4], l_[4], acc[4][6];
#pragma unroll
  for (int qi = 0; qi < 4; ++qi) {
    m_[qi] = -1e30f; l_[qi] = 0.f;
#pragma unroll
    for (int d = 0; d < 6; ++d) acc[qi][d] = 0.f;
  }

  for (int rg = sr; rg < nr; rg += 8) {         // 3-4 union rows per thread
    const float* rowp = skv + rg * RS + swq * 12;
    for (int cc = sc; cc < 25; cc += 4) {       // 6-7 own-window cols
      const float* p = rowp + cc * 12;
      const float4 A = *(const float4*)p;
      const float4 B = *(const float4*)(p + 4);
      const float4 C = *(const float4*)(p + 8);
#pragma unroll
      for (int qi = 0; qi < 4; ++qi) {
        if (rg >= srel[qi] && rg <= srel[qi] + 24) {   // block-uniform branch
          const float s = qv[qi][0]*A.x + qv[qi][1]*A.y + qv[qi][2]*A.z
                        + qv[qi][3]*A.w + qv[qi][4]*B.x + qv[qi][5]*B.y;
          float d = s - m_[qi];
          if (d > 8.0f) {                              // rare deferred rescale
            const float r2 = __expf(-d);
            l_[qi] *= r2;
            acc[qi][0] *= r2; acc[qi][1] *= r2; acc[qi][2] *= r2;
            acc[qi][3] *= r2; acc[qi][4] *= r2; acc[qi][5] *= r2;
            m_[qi] = s; d = 0.f;
          }
          const float e = __expf(d);
          l_[qi] += e;
          acc[qi][0] += e*B.z; acc[qi][1] += e*B.w; acc[qi][2] += e*C.x;
          acc[qi][3] += e*C.y; acc[qi][4] += e*C.z; acc[qi][5] += e*C.w;
        }
      }
    }
  }

  // butterfly merge over the 32 slice lanes (in-wave: slice = tid&31)
#pragma unroll
  for (int mask = 1; mask <= 16; mask <<= 1) {
#pragma unroll
    for (int qi = 0; qi < 4; ++qi) {
      const float om = __shfl_xor(m_[qi], mask), ol = __shfl_xor(l_[qi], mask);
      float oa[6];
#pragma unroll
      for (int d = 0; d < 6; ++d) oa[d] = __shfl_xor(acc[qi][d], mask);
      const float nm = fmaxf(m_[qi], om);
      const float f1 = __expf(m_[qi] - nm), f2 = __expf(om - nm);
      m_[qi] = nm;
      l_[qi] = l_[qi]*f1 + ol*f2;
#pragma unroll
      for (int d = 0; d < 6; ++d) acc[qi][d] = acc[qi][d]*f1 + oa[d]*f2;
    }
  }
  if (slice == 0) {
#pragma unroll
    for (int qi = 0; qi < 4; ++qi) {
      const float inv = 1.0f / l_[qi];
      float* ap = att + ((size_t)(h0 + qi) * W + qw) * 24 + hd * 6;
      ((float2*)ap)[0] = make_float2(acc[qi][0]*inv, acc[qi][1]*inv);
      ((float2*)ap)[1] = make_float2(acc[qi][2]*inv, acc[qi][3]*inv);
      ((float2*)ap)[2] = make_float2(acc[qi][4]*inv, acc[qi][5]*inv);
    }
  }
}

// ============================================================================
// glue_pool: y = att@Wo+bo+res; pool W-pairs; next-layer qkv on pooled px.
// ============================================================================
__global__ __launch_bounds__(256) void glue_pool(
    const float* __restrict__ att, const float* __restrict__ xres,
    const float* __restrict__ wo, const float* __restrict__ bo,
    const float* __restrict__ wq, const float* __restrict__ bq,
    float* __restrict__ xn, float* __restrict__ qn, float* __restrict__ kvn,
    int Nn)
{
  __shared__ __align__(16) float swoT[24 * 24];
  __shared__ float sbo[24];
  __shared__ __align__(16) float swqT[72 * 24];
  __shared__ float sbq[72];
  __shared__ __align__(16) float sy[128 * 28];
  const int tid = threadIdx.x;
  for (int i = tid; i < 576; i += 256) swoT[(i % 24) * 24 + i / 24] = wo[i];
  for (int i = tid; i < 1728; i += 256) swqT[(i % 72) * 24 + i / 72] = wq[i];
  if (tid < 24) sbo[tid] = bo[tid];
  if (tid < 72) sbq[tid] = bq[tid];
  __syncthreads();

  {  // phase 1: out-proj + residual for 128 source px
    const int lpx = tid >> 1, half = tid & 1;
    const size_t spx = (size_t)blockIdx.x * 128 + lpx;
    float ar[24];
    const float4* ap = (const float4*)(att + spx * 24);
#pragma unroll
    for (int i = 0; i < 6; ++i) {
      const float4 f = ap[i];
      ar[4*i] = f.x; ar[4*i+1] = f.y; ar[4*i+2] = f.z; ar[4*i+3] = f.w;
    }
    float res[12];
    const float4* rp = (const float4*)(xres + spx * 24 + half * 12);
#pragma unroll
    for (int i = 0; i < 3; ++i) {
      const float4 f = rp[i];
      res[4*i] = f.x; res[4*i+1] = f.y; res[4*i+2] = f.z; res[4*i+3] = f.w;
    }
#pragma unroll
    for (int k = 0; k < 12; ++k) {
      const int c = half * 12 + k;
      const float* wr = &swoT[c * 24];
      float acc = sbo[c] + res[k];
#pragma unroll
      for (int j = 0; j < 24; ++j) acc += ar[j] * wr[j];
      sy[lpx * 28 + c] = acc;
    }
  }
  __syncthreads();
  {  // phase 2: pool + next-layer qkv for 64 pooled px
    const int ppl = tid >> 2, jg = tid & 3;
    const size_t gp = (size_t)blockIdx.x * 64 + ppl;
    float xp[24];
    const float* y0 = &sy[(2 * ppl) * 28];
    const float* y1 = &sy[(2 * ppl + 1) * 28];
#pragma unroll
    for (int c = 0; c < 24; ++c) xp[c] = fmaxf(y0[c], y1[c]);
    if (jg == 0) {
      float4* xo = (float4*)(xn + gp * 24);
#pragma unroll
      for (int i = 0; i < 6; ++i)
        xo[i] = make_float4(xp[4*i], xp[4*i+1], xp[4*i+2], xp[4*i+3]);
    }
#pragma unroll
    for (int jj = 0; jj < 18; ++jj) {
      const int j = jg * 18 + jj;
      const float* wr = &swqT[j * 24];
      float acc = sbq[j];
#pragma unroll
      for (int c = 0; c < 24; ++c) acc += xp[c] * wr[c];
      if (j < 24)      qn[((size_t)(j / 6) * Nn + gp) * 6 + j % 6] = acc * QSCALE;
      else if (j < 48) { const int u = j - 24; kvn[((size_t)(u / 6) * Nn + gp) * 12 + u % 6] = acc; }
      else             { const int u = j - 48; kvn[((size_t)(u / 6) * Nn + gp) * 12 + 6 + u % 6] = acc; }
    }
  }
}

// ============================================================================
// glue_nopool: y = att@Wo+bo+res -> xn; next-layer qkv on y (no pooling).
// ============================================================================
__global__ __launch_bounds__(256) void glue_nopool(
    const float* __restrict__ att, const float* __restrict__ xres,
    const float* __restrict__ wo, const float* __restrict__ bo,
    const float* __restrict__ wq, const float* __restrict__ bq,
    float* __restrict__ xn, float* __restrict__ qn, float* __restrict__ kvn,
    int Nn)
{
  __shared__ __align__(16) float swoT[24 * 24];
  __shared__ float sbo[24];
  __shared__ __align__(16) float swqT[72 * 24];
  __shared__ float sbq[72];
  __shared__ __align__(16) float sy[64 * 28];
  const int tid = threadIdx.x;
  for (int i = tid; i < 576; i += 256) swoT[(i % 24) * 24 + i / 24] = wo[i];
  for (int i = tid; i < 1728; i += 256) swqT[(i % 72) * 24 + i / 72] = wq[i];
  if (tid < 24) sbo[tid] = bo[tid];
  if (tid < 72) sbq[tid] = bq[tid];
  __syncthreads();

  {  // phase 1
    const int lpx = tid >> 2, qt = tid & 3;
    const size_t spx = (size_t)blockIdx.x * 64 + lpx;
    float ar[24];
    const float4* ap = (const float4*)(att + spx * 24);
#pragma unroll
    for (int i = 0; i < 6; ++i) {
      const float4 f = ap[i];
      ar[4*i] = f.x; ar[4*i+1] = f.y; ar[4*i+2] = f.z; ar[4*i+3] = f.w;
    }
#pragma unroll
    for (int k = 0; k < 6; ++k) {
      const int c = qt * 6 + k;
      const float* wr = &swoT[c * 24];
      float acc = sbo[c] + xres[spx * 24 + c];
#pragma unroll
      for (int j = 0; j < 24; ++j) acc += ar[j] * wr[j];
      sy[lpx * 28 + c] = acc;
      xn[spx * 24 + c] = acc;
    }
  }
  __syncthreads();
  {  // phase 2
    const int lpx = tid >> 2, jg = tid & 3;
    const size_t gp = (size_t)blockIdx.x * 64 + lpx;
    const float* yr = &sy[lpx * 28];
    float xp[24];
#pragma unroll
    for (int c = 0; c < 24; ++c) xp[c] = yr[c];
#pragma unroll
    for (int jj = 0; jj < 18; ++jj) {
      const int j = jg * 18 + jj;
      const float* wr = &swqT[j * 24];
      float acc = sbq[j];
#pragma unroll
      for (int c = 0; c < 24; ++c) acc += xp[c] * wr[c];
      if (j < 24)      qn[((size_t)(j / 6) * Nn + gp) * 6 + j % 6] = acc * QSCALE;
      else if (j < 48) { const int u = j - 24; kvn[((size_t)(u / 6) * Nn + gp) * 12 + u % 6] = acc; }
      else             { const int u = j - 48; kvn[((size_t)(u / 6) * Nn + gp) * 12 + 6 + u % 6] = acc; }
    }
  }
}

// ============================================================================
// final_out: y = att@Wo+bo+res, stored transposed as dout[H][C][W].
// ============================================================================
__global__ __launch_bounds__(256) void final_out(
    const float* __restrict__ att, const float* __restrict__ xres,
    const float* __restrict__ wo, const float* __restrict__ bo,
    float* __restrict__ dout)
{
  __shared__ __align__(16) float swoT[24 * 24];
  __shared__ float sbo[24];
  const int tid = threadIdx.x;
  for (int i = tid; i < 576; i += 256) swoT[(i % 24) * 24 + i / 24] = wo[i];
  if (tid < 24) sbo[tid] = bo[tid];
  __syncthreads();
  const int lpx = tid >> 1, half = tid & 1;
  const size_t spx = (size_t)blockIdx.x * 128 + lpx;
  const int gh = (int)(spx / 88), gw = (int)(spx % 88);
  float ar[24];
  const float4* ap = (const float4*)(att + spx * 24);
#pragma unroll
  for (int i = 0; i < 6; ++i) {
    const float4 f = ap[i];
    ar[4*i] = f.x; ar[4*i+1] = f.y; ar[4*i+2] = f.z; ar[4*i+3] = f.w;
  }
  float res[12];
  const float4* rp = (const float4*)(xres + spx * 24 + half * 12);
#pragma unroll
  for (int i = 0; i < 3; ++i) {
    const float4 f = rp[i];
    res[4*i] = f.x; res[4*i+1] = f.y; res[4*i+2] = f.z; res[4*i+3] = f.w;
  }
#pragma unroll
  for (int k = 0; k < 12; ++k) {
    const int c = half * 12 + k;
    const float* wr = &swoT[c * 24];
    float acc = sbo[c] + res[k];
#pragma unroll
    for (int j = 0; j < 24; ++j) acc += ar[j] * wr[j];
    dout[((size_t)gh * 24 + c) * 88 + gw] = acc;
  }
}

// ============================================================================
extern "C" void kernel_launch(void* const* d_in, const int* in_sizes, int n_in,
                              void* d_out, int out_size, void* d_ws, size_t ws_size,
                              hipStream_t stream)
{
  const float* x      = (const float*)d_in[0];  // [64][352][24]
  const float* qkv_w  = (const float*)d_in[1];  // [4][24][72]
  const float* qkv_b  = (const float*)d_in[2];  // [4][72]
  const float* out_w  = (const float*)d_in[3];  // [4][24][24]
  const float* out_b  = (const float*)d_in[4];  // [4][24]
  float* out = (float*)d_out;                   // [64][24][88]
  float* ws = (float*)d_ws;

  const int N0 = 64 * 352, N1 = 64 * 176, N2 = 64 * 88;
  float* q   = ws;                     // [4][N][6], sized for N0
  float* kvb = q + (size_t)N0 * 24;    // [4][N][12], sized for N0
  float* att = kvb + (size_t)N0 * 48;  // [N][24], sized for N0 (reused L0..L3)
  float* x1  = att + (size_t)N0 * 24;
  float* x2  = x1 + (size_t)N1 * 24;
  float* x3  = x2 + (size_t)N2 * 24;   // total ~10.8 MB

  qkv_first<<<(N0 * 4) / 256, 256, 0, stream>>>(x, qkv_w, qkv_b, q, kvb, N0);

  attn5<<<dim3(44, 8, 4), 128, 0, stream>>>(q, kvb, att, 64, 352);
  glue_pool<<<176, 256, 0, stream>>>(att, x, out_w, out_b,
                                     qkv_w + 1728, qkv_b + 72, x1, q, kvb, N1);

  attn5<<<dim3(22, 8, 4), 128, 0, stream>>>(q, kvb, att, 64, 176);
  glue_pool<<<88, 256, 0, stream>>>(att, x1, out_w + 576, out_b + 24,
                                    qkv_w + 2 * 1728, qkv_b + 2 * 72, x2, q, kvb, N2);

  attn25<<<dim3(11, 16, 4), 256, 0, stream>>>(q, kvb, att);
  glue_nopool<<<88, 256, 0, stream>>>(att, x2, out_w + 2 * 576, out_b + 2 * 24,
                                      qkv_w + 3 * 1728, qkv_b + 3 * 72, x3, q, kvb, N2);

  attn25<<<dim3(11, 16, 4), 256, 0, stream>>>(q, kvb, att);
  final_out<<<44, 256, 0, stream>>>(att, x3, out_w + 3 * 576, out_b + 3 * 24, out);
}

// Round 7
// 152.463 us; speedup vs baseline: 1.1547x; 1.1547x over previous
//
#include <hip/hip_runtime.h>
#include <cstdint>

#define QSCALE 0.40824829046386301636f  // 6^-0.5

__device__ __forceinline__ float2 pk_fma(float2 a, float2 b, float2 c) {
  return make_float2(fmaf(a.x, b.x, c.x), fmaf(a.y, b.y, c.y));
}
__device__ __forceinline__ float2 pk_mul(float2 a, float2 b) {
  return make_float2(a.x * b.x, a.y * b.y);
}

// ============================================================================
// qkv_first: x[N][24] -> q[4][N][6] (pre-scaled), kv[4][N][12] ({k6,v6})
// ============================================================================
__global__ __launch_bounds__(256) void qkv_first(
    const float* __restrict__ x, const float* __restrict__ w,
    const float* __restrict__ b, float* __restrict__ q,
    float* __restrict__ kv, int npx)
{
  __shared__ __align__(16) float swT[72 * 24];  // transposed: swT[j][c]
  __shared__ float sb[72];
  for (int i = threadIdx.x; i < 1728; i += 256) swT[(i % 72) * 24 + i / 72] = w[i];
  if (threadIdx.x < 72) sb[threadIdx.x] = b[threadIdx.x];
  __syncthreads();
  const int t = blockIdx.x * 256 + threadIdx.x;
  const int p = t >> 2, jg = t & 3;
  if (p >= npx) return;
  float xr[24];
  const float4* xp = (const float4*)(x + (size_t)p * 24);
#pragma unroll
  for (int i = 0; i < 6; ++i) {
    const float4 f = xp[i];
    xr[4*i] = f.x; xr[4*i+1] = f.y; xr[4*i+2] = f.z; xr[4*i+3] = f.w;
  }
#pragma unroll
  for (int jj = 0; jj < 18; ++jj) {
    const int j = jg * 18 + jj;
    const float* wr = &swT[j * 24];
    float acc = sb[j];
#pragma unroll
    for (int c = 0; c < 24; ++c) acc += xr[c] * wr[c];
    if (j < 24)      q[((size_t)(j / 6) * npx + p) * 6 + j % 6] = acc * QSCALE;
    else if (j < 48) { const int u = j - 24; kv[((size_t)(u / 6) * npx + p) * 12 + u % 6] = acc; }
    else             { const int u = j - 48; kv[((size_t)(u / 6) * npx + p) * 12 + 6 + u % 6] = acc; }
  }
}

// ============================================================================
// attn5_fused: win=5 layer, ALL 4 heads per block + fused glue.
// Block = 8x8 px, 256 thr.  LDS K/V: 4 planes x 1732 f (pad -> minimal bank
// load: starts 4*((head+3*ql)%8) uniform).  Attention thread = (px, head),
// 25 keys, direct-exp softmax (no max: |s| << 88).  Then out-proj+residual,
// W-maxpool, next-layer qkv (ping-pong buffers, no cross-block hazard).
// ============================================================================
__global__ __launch_bounds__(256) void attn5_fused(
    const float* __restrict__ q, const float* __restrict__ kvb,
    const float* __restrict__ xres,
    const float* __restrict__ wo, const float* __restrict__ bo,
    const float* __restrict__ wq, const float* __restrict__ bq,
    float* __restrict__ xn, float* __restrict__ qn, float* __restrict__ kvn,
    int H, int W, int Nn)
{
  __shared__ __align__(16) float skv[4 * 1732];   // 27.7 KB
  __shared__ __align__(16) float satt[64 * 28];
  __shared__ __align__(16) float swoT[24 * 24];
  __shared__ float sbo[24];
  __shared__ __align__(16) float swqT[72 * 24];
  __shared__ float sbq[72];

  const int tid = threadIdx.x;
  const int h0 = blockIdx.y * 8, w0 = blockIdx.x * 8;
  const int N = H * W;

  for (int i = tid; i < 576; i += 256) swoT[(i % 24) * 24 + i / 24] = wo[i];
  for (int i = tid; i < 1728; i += 256) swqT[(i % 72) * 24 + i / 72] = wq[i];
  if (tid < 24) sbo[tid] = bo[tid];
  if (tid < 72) sbq[tid] = bq[tid];

  const int rlo = min(max(h0 - 2, 0), H - 5);
  const int nr  = min(max(h0 + 5, 0), H - 5) + 4 - rlo + 1;   // <= 12
  const int clo = min(max(w0 - 2, 0), W - 5);
  const int nc  = min(max(w0 + 5, 0), W - 5) + 4 - clo + 1;   // <= 12
  const int ncc = nc * 3;
  for (int i = tid; i < nr * ncc; i += 256) {
    const int r = i / ncc, c4 = i - r * ncc;
    const size_t goff = ((size_t)(rlo + r) * W + clo) * 12;
#pragma unroll
    for (int h = 0; h < 4; ++h) {
      const float4 v = ((const float4*)(kvb + (size_t)h * N * 12 + goff))[c4];
      ((float4*)skv)[h * 433 + r * 36 + c4] = v;   // plane 433 f4, row 36 f4
    }
  }
  __syncthreads();

  {  // ---- attention: thread = (px, head); 25 keys, direct exp ----
    const int ql = tid >> 2, head = tid & 3;
    const int qh = h0 + (ql >> 3), qw = w0 + (ql & 7);
    const float* qp = q + ((size_t)head * N + (size_t)qh * W + qw) * 6;
    const float2 q01 = *(const float2*)qp;
    const float2 q23 = *(const float2*)(qp + 2);
    const float2 q45 = *(const float2*)(qp + 4);
    const int shq = min(max(qh - 2, 0), H - 5) - rlo;
    const int swq = min(max(qw - 2, 0), W - 5) - clo;
    const float* plane = skv + head * 1732;

    float l = 0.f;
    float2 a01 = make_float2(0, 0), a23 = make_float2(0, 0), a45 = make_float2(0, 0);
#pragma unroll
    for (int rr = 0; rr < 5; ++rr) {
      const float* rowp = plane + (shq + rr) * 144 + swq * 12;
#pragma unroll
      for (int cc = 0; cc < 5; ++cc) {
        const float* p = rowp + cc * 12;
        const float4 A = *(const float4*)p;
        const float4 B = *(const float4*)(p + 4);
        const float4 C = *(const float4*)(p + 8);
        float2 t = pk_mul(q01, make_float2(A.x, A.y));
        t = pk_fma(q23, make_float2(A.z, A.w), t);
        t = pk_fma(q45, make_float2(B.x, B.y), t);
        const float e = __expf(t.x + t.y);
        l += e;
        const float2 e2 = make_float2(e, e);
        a01 = pk_fma(e2, make_float2(B.z, B.w), a01);
        a23 = pk_fma(e2, make_float2(C.x, C.y), a23);
        a45 = pk_fma(e2, make_float2(C.z, C.w), a45);
      }
    }
    const float inv = 1.0f / l;
    float* ao = satt + ql * 28 + head * 6;
    ((float2*)ao)[0] = make_float2(a01.x * inv, a01.y * inv);
    ((float2*)ao)[1] = make_float2(a23.x * inv, a23.y * inv);
    ((float2*)ao)[2] = make_float2(a45.x * inv, a45.y * inv);
  }
  __syncthreads();

  float* sy = skv;  // alias (skv dead): [64][28]
  {  // ---- phase 1: out-proj + residual for 64 px ----
    const int px = tid >> 2, qt = tid & 3;
    const int gh = h0 + (px >> 3), gw = w0 + (px & 7);
    const float* ar = satt + px * 28;
    float a[24];
#pragma unroll
    for (int j = 0; j < 24; ++j) a[j] = ar[j];
    const float* resp = xres + ((size_t)gh * W + gw) * 24;
#pragma unroll
    for (int k = 0; k < 6; ++k) {
      const int c = qt * 6 + k;
      const float* wr = &swoT[c * 24];
      float acc = sbo[c] + resp[c];
#pragma unroll
      for (int j = 0; j < 24; ++j) acc += a[j] * wr[j];
      sy[px * 28 + c] = acc;
    }
  }
  __syncthreads();

  {  // ---- phase 2: W-maxpool pairs + next-layer qkv on 32 pooled px ----
    const int pp = tid >> 3, jg = tid & 7;       // pp: pr*4+pc
    const int pr = pp >> 2, pc = pp & 3;
    const float* y0 = &sy[(pr * 8 + 2 * pc) * 28];
    const float* y1 = &sy[(pr * 8 + 2 * pc + 1) * 28];
    float xp[24];
#pragma unroll
    for (int c = 0; c < 24; ++c) xp[c] = fmaxf(y0[c], y1[c]);
    const int Wn = W >> 1;
    const size_t gp = (size_t)(h0 + pr) * Wn + (w0 >> 1) + pc;
    if (jg == 0) {
      float4* xo = (float4*)(xn + gp * 24);
#pragma unroll
      for (int i = 0; i < 6; ++i)
        xo[i] = make_float4(xp[4*i], xp[4*i+1], xp[4*i+2], xp[4*i+3]);
    }
#pragma unroll
    for (int jj = 0; jj < 9; ++jj) {
      const int j = jg * 9 + jj;
      const float* wr = &swqT[j * 24];
      float acc = sbq[j];
#pragma unroll
      for (int c = 0; c < 24; ++c) acc += xp[c] * wr[c];
      if (j < 24)      qn[((size_t)(j / 6) * Nn + gp) * 6 + j % 6] = acc * QSCALE;
      else if (j < 48) { const int u = j - 24; kvn[((size_t)(u / 6) * Nn + gp) * 12 + u % 6] = acc; }
      else             { const int u = j - 48; kvn[((size_t)(u / 6) * Nn + gp) * 12 + 6 + u % 6] = acc; }
    }
  }
}

// ============================================================================
// attn25: win=25, one head per block.  Block = 4x8 q, 256 thr = qw(8) x
// slice(32 = sr8 x sc4).  4 query rows in registers; union rows staged once
// (stride 388 -> minimal bank load); direct-exp softmax (no max; |s| << 88);
// sum-only butterfly merge over 32 slice lanes.
// ============================================================================
__global__ __launch_bounds__(256) void attn25(
    const float* __restrict__ q, const float* __restrict__ kv,
    float* __restrict__ att)
{
  constexpr int H = 64, W = 88, N = H * W;
  constexpr int RS = 388;
  __shared__ __align__(16) float skv[28 * RS];  // 43.5 KB
  const int tid = threadIdx.x;
  const int h0 = blockIdx.y * 4, w0 = blockIdx.x * 8, hd = blockIdx.z;
  const int rlo = min(max(h0 - 12, 0), H - 25);
  const int nr  = min(max(h0 + 3 - 12, 0), H - 25) + 24 - rlo + 1;  // <= 28
  const int clo = min(max(w0 - 12, 0), W - 25);
  const int nc  = min(max(w0 + 7 - 12, 0), W - 25) + 24 - clo + 1;  // <= 32
  const float* kvh = kv + (size_t)hd * N * 12;
  const int ncc = nc * 3;
  for (int i = tid; i < nr * ncc; i += 256) {
    const int r = i / ncc, c4 = i - r * ncc;
    const float4 v = ((const float4*)(kvh + ((size_t)(rlo + r) * W + clo) * 12))[c4];
    ((float4*)skv)[r * (RS / 4) + c4] = v;
  }
  __syncthreads();

  const int qw_ = tid >> 5, slice = tid & 31, sr = slice >> 2, sc = slice & 3;
  const int qw = w0 + qw_;
  const int swq = min(max(qw - 12, 0), W - 25) - clo;   // 0..7

  float2 q01[4], q23[4], q45[4];
  int srel[4];
#pragma unroll
  for (int qi = 0; qi < 4; ++qi) {
    const float* qp = q + ((size_t)hd * N + (size_t)(h0 + qi) * W + qw) * 6;
    q01[qi] = *(const float2*)qp;
    q23[qi] = *(const float2*)(qp + 2);
    q45[qi] = *(const float2*)(qp + 4);
    srel[qi] = min(max(h0 + qi - 12, 0), H - 25) - rlo;  // block-uniform, 0..3
  }

  float l_[4];
  float2 a01[4], a23[4], a45[4];
#pragma unroll
  for (int qi = 0; qi < 4; ++qi) {
    l_[qi] = 0.f;
    a01[qi] = make_float2(0, 0); a23[qi] = make_float2(0, 0); a45[qi] = make_float2(0, 0);
  }

  for (int rg = sr; rg < nr; rg += 8) {         // 3-4 union rows per thread
    const float* rowp = skv + rg * RS + swq * 12;
    for (int cc = sc; cc < 25; cc += 4) {       // 6-7 own-window cols
      const float* p = rowp + cc * 12;
      const float4 A = *(const float4*)p;
      const float4 B = *(const float4*)(p + 4);
      const float4 C = *(const float4*)(p + 8);
      const float2 k01 = make_float2(A.x, A.y);
      const float2 k23 = make_float2(A.z, A.w);
      const float2 k45 = make_float2(B.x, B.y);
      const float2 v01 = make_float2(B.z, B.w);
      const float2 v23 = make_float2(C.x, C.y);
      const float2 v45 = make_float2(C.z, C.w);
#pragma unroll
      for (int qi = 0; qi < 4; ++qi) {
        if (rg >= srel[qi] && rg <= srel[qi] + 24) {   // block-uniform branch
          float2 t = pk_mul(q01[qi], k01);
          t = pk_fma(q23[qi], k23, t);
          t = pk_fma(q45[qi], k45, t);
          const float e = __expf(t.x + t.y);
          l_[qi] += e;
          const float2 e2 = make_float2(e, e);
          a01[qi] = pk_fma(e2, v01, a01[qi]);
          a23[qi] = pk_fma(e2, v23, a23[qi]);
          a45[qi] = pk_fma(e2, v45, a45[qi]);
        }
      }
    }
  }

  // sum-only butterfly over 32 slice lanes
#pragma unroll
  for (int mask = 1; mask <= 16; mask <<= 1) {
#pragma unroll
    for (int qi = 0; qi < 4; ++qi) {
      l_[qi] += __shfl_xor(l_[qi], mask);
      a01[qi].x += __shfl_xor(a01[qi].x, mask);
      a01[qi].y += __shfl_xor(a01[qi].y, mask);
      a23[qi].x += __shfl_xor(a23[qi].x, mask);
      a23[qi].y += __shfl_xor(a23[qi].y, mask);
      a45[qi].x += __shfl_xor(a45[qi].x, mask);
      a45[qi].y += __shfl_xor(a45[qi].y, mask);
    }
  }
  if (slice == 0) {
#pragma unroll
    for (int qi = 0; qi < 4; ++qi) {
      const float inv = 1.0f / l_[qi];
      float* ap = att + ((size_t)(h0 + qi) * W + qw) * 24 + hd * 6;
      ((float2*)ap)[0] = make_float2(a01[qi].x * inv, a01[qi].y * inv);
      ((float2*)ap)[1] = make_float2(a23[qi].x * inv, a23[qi].y * inv);
      ((float2*)ap)[2] = make_float2(a45[qi].x * inv, a45[qi].y * inv);
    }
  }
}

// ============================================================================
// glue_nopool: y = att@Wo+bo+res -> xn; next-layer qkv on y (no pooling).
// ============================================================================
__global__ __launch_bounds__(256) void glue_nopool(
    const float* __restrict__ att, const float* __restrict__ xres,
    const float* __restrict__ wo, const float* __restrict__ bo,
    const float* __restrict__ wq, const float* __restrict__ bq,
    float* __restrict__ xn, float* __restrict__ qn, float* __restrict__ kvn,
    int Nn)
{
  __shared__ __align__(16) float swoT[24 * 24];
  __shared__ float sbo[24];
  __shared__ __align__(16) float swqT[72 * 24];
  __shared__ float sbq[72];
  __shared__ __align__(16) float sy[64 * 28];
  const int tid = threadIdx.x;
  for (int i = tid; i < 576; i += 256) swoT[(i % 24) * 24 + i / 24] = wo[i];
  for (int i = tid; i < 1728; i += 256) swqT[(i % 72) * 24 + i / 72] = wq[i];
  if (tid < 24) sbo[tid] = bo[tid];
  if (tid < 72) sbq[tid] = bq[tid];
  __syncthreads();

  {  // phase 1
    const int lpx = tid >> 2, qt = tid & 3;
    const size_t spx = (size_t)blockIdx.x * 64 + lpx;
    float ar[24];
    const float4* ap = (const float4*)(att + spx * 24);
#pragma unroll
    for (int i = 0; i < 6; ++i) {
      const float4 f = ap[i];
      ar[4*i] = f.x; ar[4*i+1] = f.y; ar[4*i+2] = f.z; ar[4*i+3] = f.w;
    }
#pragma unroll
    for (int k = 0; k < 6; ++k) {
      const int c = qt * 6 + k;
      const float* wr = &swoT[c * 24];
      float acc = sbo[c] + xres[spx * 24 + c];
#pragma unroll
      for (int j = 0; j < 24; ++j) acc += ar[j] * wr[j];
      sy[lpx * 28 + c] = acc;
      xn[spx * 24 + c] = acc;
    }
  }
  __syncthreads();
  {  // phase 2
    const int lpx = tid >> 2, jg = tid & 3;
    const size_t gp = (size_t)blockIdx.x * 64 + lpx;
    const float* yr = &sy[lpx * 28];
    float xp[24];
#pragma unroll
    for (int c = 0; c < 24; ++c) xp[c] = yr[c];
#pragma unroll
    for (int jj = 0; jj < 18; ++jj) {
      const int j = jg * 18 + jj;
      const float* wr = &swqT[j * 24];
      float acc = sbq[j];
#pragma unroll
      for (int c = 0; c < 24; ++c) acc += xp[c] * wr[c];
      if (j < 24)      qn[((size_t)(j / 6) * Nn + gp) * 6 + j % 6] = acc * QSCALE;
      else if (j < 48) { const int u = j - 24; kvn[((size_t)(u / 6) * Nn + gp) * 12 + u % 6] = acc; }
      else             { const int u = j - 48; kvn[((size_t)(u / 6) * Nn + gp) * 12 + 6 + u % 6] = acc; }
    }
  }
}

// ============================================================================
// final_out: y = att@Wo+bo+res, stored transposed as dout[H][C][W].
// ============================================================================
__global__ __launch_bounds__(256) void final_out(
    const float* __restrict__ att, const float* __restrict__ xres,
    const float* __restrict__ wo, const float* __restrict__ bo,
    float* __restrict__ dout)
{
  __shared__ __align__(16) float swoT[24 * 24];
  __shared__ float sbo[24];
  const int tid = threadIdx.x;
  for (int i = tid; i < 576; i += 256) swoT[(i % 24) * 24 + i / 24] = wo[i];
  if (tid < 24) sbo[tid] = bo[tid];
  __syncthreads();
  const int lpx = tid >> 1, half = tid & 1;
  const size_t spx = (size_t)blockIdx.x * 128 + lpx;
  const int gh = (int)(spx / 88), gw = (int)(spx % 88);
  float ar[24];
  const float4* ap = (const float4*)(att + spx * 24);
#pragma unroll
  for (int i = 0; i < 6; ++i) {
    const float4 f = ap[i];
    ar[4*i] = f.x; ar[4*i+1] = f.y; ar[4*i+2] = f.z; ar[4*i+3] = f.w;
  }
  float res[12];
  const float4* rp = (const float4*)(xres + spx * 24 + half * 12);
#pragma unroll
  for (int i = 0; i < 3; ++i) {
    const float4 f = rp[i];
    res[4*i] = f.x; res[4*i+1] = f.y; res[4*i+2] = f.z; res[4*i+3] = f.w;
  }
#pragma unroll
  for (int k = 0; k < 12; ++k) {
    const int c = half * 12 + k;
    const float* wr = &swoT[c * 24];
    float acc = sbo[c] + res[k];
#pragma unroll
    for (int j = 0; j < 24; ++j) acc += ar[j] * wr[j];
    dout[((size_t)gh * 24 + c) * 88 + gw] = acc;
  }
}

// ============================================================================
extern "C" void kernel_launch(void* const* d_in, const int* in_sizes, int n_in,
                              void* d_out, int out_size, void* d_ws, size_t ws_size,
                              hipStream_t stream)
{
  const float* x      = (const float*)d_in[0];  // [64][352][24]
  const float* qkv_w  = (const float*)d_in[1];  // [4][24][72]
  const float* qkv_b  = (const float*)d_in[2];  // [4][72]
  const float* out_w  = (const float*)d_in[3];  // [4][24][24]
  const float* out_b  = (const float*)d_in[4];  // [4][24]
  float* out = (float*)d_out;                   // [64][24][88]
  float* ws = (float*)d_ws;

  const int N0 = 64 * 352, N1 = 64 * 176, N2 = 64 * 88;
  float* q_a  = ws;                        // [4][N][6]  (ping)
  float* kv_a = q_a + (size_t)N0 * 24;     // [4][N][12] (ping)
  float* q_b  = kv_a + (size_t)N0 * 48;    // (pong, sized N1)
  float* kv_b = q_b + (size_t)N1 * 24;
  float* att  = kv_b + (size_t)N1 * 48;    // [N][24] scratch (sized N0)
  float* x1   = att + (size_t)N0 * 24;
  float* x2   = x1 + (size_t)N1 * 24;
  float* x3   = x2 + (size_t)N2 * 24;      // total ~14 MB

  qkv_first<<<(N0 * 4) / 256, 256, 0, stream>>>(x, qkv_w, qkv_b, q_a, kv_a, N0);

  attn5_fused<<<dim3(44, 8), 256, 0, stream>>>(
      q_a, kv_a, x, out_w, out_b, qkv_w + 1728, qkv_b + 72,
      x1, q_b, kv_b, 64, 352, N1);

  attn5_fused<<<dim3(22, 8), 256, 0, stream>>>(
      q_b, kv_b, x1, out_w + 576, out_b + 24, qkv_w + 2 * 1728, qkv_b + 2 * 72,
      x2, q_a, kv_a, 64, 176, N2);

  attn25<<<dim3(11, 16, 4), 256, 0, stream>>>(q_a, kv_a, att);
  glue_nopool<<<88, 256, 0, stream>>>(att, x2, out_w + 2 * 576, out_b + 2 * 24,
                                      qkv_w + 3 * 1728, qkv_b + 3 * 72, x3, q_b, kv_b, N2);

  attn25<<<dim3(11, 16, 4), 256, 0, stream>>>(q_b, kv_b, att);
  final_out<<<44, 256, 0, stream>>>(att, x3, out_w + 3 * 576, out_b + 3 * 24, out);
}

// Round 8
// 149.432 us; speedup vs baseline: 1.1782x; 1.0203x over previous
//
#include <hip/hip_runtime.h>
#include <cstdint>

// q pre-scale: 6^-0.5 * log2(e)  (scores become log2-domain -> bare v_exp_f32)
#define QS2 0.58897146057486810f

#if __has_builtin(__builtin_amdgcn_exp2f)
#define EXP2(x) __builtin_amdgcn_exp2f(x)
#else
#define EXP2(x) exp2f(x)
#endif

__device__ __forceinline__ float2 pk_fma(float2 a, float2 b, float2 c) {
  return make_float2(fmaf(a.x, b.x, c.x), fmaf(a.y, b.y, c.y));
}
__device__ __forceinline__ float2 pk_mul(float2 a, float2 b) {
  return make_float2(a.x * b.x, a.y * b.y);
}

// ============================================================================
// qkv_first: x[N][24] -> q[4][N][6] (pre-scaled by QS2), kv[4][N][12]
// ============================================================================
__global__ __launch_bounds__(256) void qkv_first(
    const float* __restrict__ x, const float* __restrict__ w,
    const float* __restrict__ b, float* __restrict__ q,
    float* __restrict__ kv, int npx)
{
  __shared__ __align__(16) float swT[72 * 24];  // transposed: swT[j][c]
  __shared__ float sb[72];
  for (int i = threadIdx.x; i < 1728; i += 256) swT[(i % 72) * 24 + i / 72] = w[i];
  if (threadIdx.x < 72) sb[threadIdx.x] = b[threadIdx.x];
  __syncthreads();
  const int t = blockIdx.x * 256 + threadIdx.x;
  const int p = t >> 2, jg = t & 3;
  if (p >= npx) return;
  float xr[24];
  const float4* xp = (const float4*)(x + (size_t)p * 24);
#pragma unroll
  for (int i = 0; i < 6; ++i) {
    const float4 f = xp[i];
    xr[4*i] = f.x; xr[4*i+1] = f.y; xr[4*i+2] = f.z; xr[4*i+3] = f.w;
  }
#pragma unroll
  for (int jj = 0; jj < 18; ++jj) {
    const int j = jg * 18 + jj;
    const float* wr = &swT[j * 24];
    float acc = sb[j];
#pragma unroll
    for (int c = 0; c < 24; ++c) acc += xr[c] * wr[c];
    if (j < 24)      q[((size_t)(j / 6) * npx + p) * 6 + j % 6] = acc * QS2;
    else if (j < 48) { const int u = j - 24; kv[((size_t)(u / 6) * npx + p) * 12 + u % 6] = acc; }
    else             { const int u = j - 48; kv[((size_t)(u / 6) * npx + p) * 12 + 6 + u % 6] = acc; }
  }
}

// ============================================================================
// attn5_fused: win=5 layer, ALL 4 heads per block + fused glue.
// Block = 8x8 px, 256 thr.  Direct-exp2 softmax.  Fuses out-proj + residual +
// W-maxpool + next-layer qkv (ping-pong buffers).
// ============================================================================
__global__ __launch_bounds__(256) void attn5_fused(
    const float* __restrict__ q, const float* __restrict__ kvb,
    const float* __restrict__ xres,
    const float* __restrict__ wo, const float* __restrict__ bo,
    const float* __restrict__ wq, const float* __restrict__ bq,
    float* __restrict__ xn, float* __restrict__ qn, float* __restrict__ kvn,
    int H, int W, int Nn)
{
  __shared__ __align__(16) float skv[4 * 1732];   // 27.7 KB
  __shared__ __align__(16) float satt[64 * 28];
  __shared__ __align__(16) float swoT[24 * 24];
  __shared__ float sbo[24];
  __shared__ __align__(16) float swqT[72 * 24];
  __shared__ float sbq[72];

  const int tid = threadIdx.x;
  const int h0 = blockIdx.y * 8, w0 = blockIdx.x * 8;
  const int N = H * W;

  for (int i = tid; i < 576; i += 256) swoT[(i % 24) * 24 + i / 24] = wo[i];
  for (int i = tid; i < 1728; i += 256) swqT[(i % 72) * 24 + i / 72] = wq[i];
  if (tid < 24) sbo[tid] = bo[tid];
  if (tid < 72) sbq[tid] = bq[tid];

  const int rlo = min(max(h0 - 2, 0), H - 5);
  const int nr  = min(max(h0 + 5, 0), H - 5) + 4 - rlo + 1;   // <= 12
  const int clo = min(max(w0 - 2, 0), W - 5);
  const int nc  = min(max(w0 + 5, 0), W - 5) + 4 - clo + 1;   // <= 12
  const int ncc = nc * 3;
  for (int i = tid; i < nr * ncc; i += 256) {
    const int r = i / ncc, c4 = i - r * ncc;
    const size_t goff = ((size_t)(rlo + r) * W + clo) * 12;
#pragma unroll
    for (int h = 0; h < 4; ++h) {
      const float4 v = ((const float4*)(kvb + (size_t)h * N * 12 + goff))[c4];
      ((float4*)skv)[h * 433 + r * 36 + c4] = v;   // plane 433 f4, row 36 f4
    }
  }
  __syncthreads();

  {  // ---- attention: thread = (px, head); 25 keys, direct exp2 ----
    const int ql = tid >> 2, head = tid & 3;
    const int qh = h0 + (ql >> 3), qw = w0 + (ql & 7);
    const float* qp = q + ((size_t)head * N + (size_t)qh * W + qw) * 6;
    const float2 q01 = *(const float2*)qp;
    const float2 q23 = *(const float2*)(qp + 2);
    const float2 q45 = *(const float2*)(qp + 4);
    const int shq = min(max(qh - 2, 0), H - 5) - rlo;
    const int swq = min(max(qw - 2, 0), W - 5) - clo;
    const float* plane = skv + head * 1732;

    float l = 0.f;
    float2 a01 = make_float2(0, 0), a23 = make_float2(0, 0), a45 = make_float2(0, 0);
#pragma unroll
    for (int rr = 0; rr < 5; ++rr) {
      const float* rowp = plane + (shq + rr) * 144 + swq * 12;
#pragma unroll
      for (int cc = 0; cc < 5; ++cc) {
        const float* p = rowp + cc * 12;
        const float4 A = *(const float4*)p;
        const float4 B = *(const float4*)(p + 4);
        const float4 C = *(const float4*)(p + 8);
        float2 t = pk_mul(q01, make_float2(A.x, A.y));
        t = pk_fma(q23, make_float2(A.z, A.w), t);
        t = pk_fma(q45, make_float2(B.x, B.y), t);
        const float e = EXP2(t.x + t.y);
        l += e;
        const float2 e2 = make_float2(e, e);
        a01 = pk_fma(e2, make_float2(B.z, B.w), a01);
        a23 = pk_fma(e2, make_float2(C.x, C.y), a23);
        a45 = pk_fma(e2, make_float2(C.z, C.w), a45);
      }
    }
    const float inv = 1.0f / l;
    float* ao = satt + ql * 28 + head * 6;
    ((float2*)ao)[0] = make_float2(a01.x * inv, a01.y * inv);
    ((float2*)ao)[1] = make_float2(a23.x * inv, a23.y * inv);
    ((float2*)ao)[2] = make_float2(a45.x * inv, a45.y * inv);
  }
  __syncthreads();

  float* sy = skv;  // alias (skv dead): [64][28]
  {  // ---- phase 1: out-proj + residual for 64 px ----
    const int px = tid >> 2, qt = tid & 3;
    const int gh = h0 + (px >> 3), gw = w0 + (px & 7);
    const float* ar = satt + px * 28;
    float a[24];
#pragma unroll
    for (int j = 0; j < 24; ++j) a[j] = ar[j];
    const float* resp = xres + ((size_t)gh * W + gw) * 24;
#pragma unroll
    for (int k = 0; k < 6; ++k) {
      const int c = qt * 6 + k;
      const float* wr = &swoT[c * 24];
      float acc = sbo[c] + resp[c];
#pragma unroll
      for (int j = 0; j < 24; ++j) acc += a[j] * wr[j];
      sy[px * 28 + c] = acc;
    }
  }
  __syncthreads();

  {  // ---- phase 2: W-maxpool pairs + next-layer qkv on 32 pooled px ----
    const int pp = tid >> 3, jg = tid & 7;       // pp: pr*4+pc
    const int pr = pp >> 2, pc = pp & 3;
    const float* y0 = &sy[(pr * 8 + 2 * pc) * 28];
    const float* y1 = &sy[(pr * 8 + 2 * pc + 1) * 28];
    float xp[24];
#pragma unroll
    for (int c = 0; c < 24; ++c) xp[c] = fmaxf(y0[c], y1[c]);
    const int Wn = W >> 1;
    const size_t gp = (size_t)(h0 + pr) * Wn + (w0 >> 1) + pc;
    if (jg == 0) {
      float4* xo = (float4*)(xn + gp * 24);
#pragma unroll
      for (int i = 0; i < 6; ++i)
        xo[i] = make_float4(xp[4*i], xp[4*i+1], xp[4*i+2], xp[4*i+3]);
    }
#pragma unroll
    for (int jj = 0; jj < 9; ++jj) {
      const int j = jg * 9 + jj;
      const float* wr = &swqT[j * 24];
      float acc = sbq[j];
#pragma unroll
      for (int c = 0; c < 24; ++c) acc += xp[c] * wr[c];
      if (j < 24)      qn[((size_t)(j / 6) * Nn + gp) * 6 + j % 6] = acc * QS2;
      else if (j < 48) { const int u = j - 24; kvn[((size_t)(u / 6) * Nn + gp) * 12 + u % 6] = acc; }
      else             { const int u = j - 48; kvn[((size_t)(u / 6) * Nn + gp) * 12 + 6 + u % 6] = acc; }
    }
  }
}

// ============================================================================
// attn25: win=25, one head per block.  Block = 4x8 q, 256 thr = qw(8) x
// slice(32 = sr8 x sc4).  4 query rows in registers; union staged once.
// Inner col loop FULLY UNROLLED (7 iters, last masked) -> all ds_reads of a
// row batch-issued (ILP hides LDS latency).  Branchless validity (cndmask on
// e, NaN-safe bit-select).  Direct exp2.  Butterfly merge over 32 lanes.
// ============================================================================
__global__ __launch_bounds__(256) void attn25(
    const float* __restrict__ q, const float* __restrict__ kv,
    float* __restrict__ att)
{
  constexpr int H = 64, W = 88, N = H * W;
  constexpr int RS = 388;
  __shared__ __align__(16) float skv[28 * RS + 48];  // +pad for masked OOB reads
  const int tid = threadIdx.x;
  const int h0 = blockIdx.y * 4, w0 = blockIdx.x * 8, hd = blockIdx.z;
  const int rlo = min(max(h0 - 12, 0), H - 25);
  const int nr  = min(max(h0 + 3 - 12, 0), H - 25) + 24 - rlo + 1;  // 25..28
  const int clo = min(max(w0 - 12, 0), W - 25);
  const int nc  = min(max(w0 + 7 - 12, 0), W - 25) + 24 - clo + 1;  // 25..32
  const float* kvh = kv + (size_t)hd * N * 12;
  const int ncc = nc * 3;
  for (int i = tid; i < nr * ncc; i += 256) {
    const int r = i / ncc, c4 = i - r * ncc;
    const float4 v = ((const float4*)(kvh + ((size_t)(rlo + r) * W + clo) * 12))[c4];
    ((float4*)skv)[r * (RS / 4) + c4] = v;
  }
  __syncthreads();

  const int qw_ = tid >> 5, slice = tid & 31, sr = slice >> 2, sc = slice & 3;
  const int qw = w0 + qw_;
  const int swq = min(max(qw - 12, 0), W - 25) - clo;   // 0..7

  float2 q01[4], q23[4], q45[4];
  int srel[4];
#pragma unroll
  for (int qi = 0; qi < 4; ++qi) {
    const float* qp = q + ((size_t)hd * N + (size_t)(h0 + qi) * W + qw) * 6;
    q01[qi] = *(const float2*)qp;
    q23[qi] = *(const float2*)(qp + 2);
    q45[qi] = *(const float2*)(qp + 4);
    srel[qi] = min(max(h0 + qi - 12, 0), H - 25) - rlo;  // 0..3
  }

  float l_[4];
  float2 a01[4], a23[4], a45[4];
#pragma unroll
  for (int qi = 0; qi < 4; ++qi) {
    l_[qi] = 0.f;
    a01[qi] = make_float2(0, 0); a23[qi] = make_float2(0, 0); a45[qi] = make_float2(0, 0);
  }

  for (int rg = sr; rg < nr; rg += 8) {         // 3-4 union rows per thread
    const float* rowp = skv + rg * RS + swq * 12;
    bool vq[4];
#pragma unroll
    for (int qi = 0; qi < 4; ++qi)
      vq[qi] = (rg >= srel[qi]) && (rg <= srel[qi] + 24);
#pragma unroll
    for (int j = 0; j < 7; ++j) {               // cc = sc + 4j, last masked
      const int cc = sc + 4 * j;
      const float* p = rowp + cc * 12;
      const float4 A = *(const float4*)p;
      const float4 B = *(const float4*)(p + 4);
      const float4 C = *(const float4*)(p + 8);
      const float2 k01 = make_float2(A.x, A.y);
      const float2 k23 = make_float2(A.z, A.w);
      const float2 k45 = make_float2(B.x, B.y);
      const float2 v01 = make_float2(B.z, B.w);
      const float2 v23 = make_float2(C.x, C.y);
      const float2 v45 = make_float2(C.z, C.w);
#pragma unroll
      for (int qi = 0; qi < 4; ++qi) {
        float2 t = pk_mul(q01[qi], k01);
        t = pk_fma(q23[qi], k23, t);
        t = pk_fma(q45[qi], k45, t);
        float e = EXP2(t.x + t.y);
        const bool ok = (j < 6) ? vq[qi] : (vq[qi] && cc < 25);
        e = ok ? e : 0.0f;                       // bit-select, NaN-safe
        l_[qi] += e;
        const float2 e2 = make_float2(e, e);
        a01[qi] = pk_fma(e2, v01, a01[qi]);
        a23[qi] = pk_fma(e2, v23, a23[qi]);
        a45[qi] = pk_fma(e2, v45, a45[qi]);
      }
    }
  }

  // sum-only butterfly over 32 slice lanes
#pragma unroll
  for (int mask = 1; mask <= 16; mask <<= 1) {
#pragma unroll
    for (int qi = 0; qi < 4; ++qi) {
      l_[qi] += __shfl_xor(l_[qi], mask);
      a01[qi].x += __shfl_xor(a01[qi].x, mask);
      a01[qi].y += __shfl_xor(a01[qi].y, mask);
      a23[qi].x += __shfl_xor(a23[qi].x, mask);
      a23[qi].y += __shfl_xor(a23[qi].y, mask);
      a45[qi].x += __shfl_xor(a45[qi].x, mask);
      a45[qi].y += __shfl_xor(a45[qi].y, mask);
    }
  }
  if (slice == 0) {
#pragma unroll
    for (int qi = 0; qi < 4; ++qi) {
      const float inv = 1.0f / l_[qi];
      float* ap = att + ((size_t)(h0 + qi) * W + qw) * 24 + hd * 6;
      ((float2*)ap)[0] = make_float2(a01[qi].x * inv, a01[qi].y * inv);
      ((float2*)ap)[1] = make_float2(a23[qi].x * inv, a23[qi].y * inv);
      ((float2*)ap)[2] = make_float2(a45[qi].x * inv, a45[qi].y * inv);
    }
  }
}

// ============================================================================
// glue_nopool: y = att@Wo+bo+res -> xn; next-layer qkv on y (no pooling).
// ============================================================================
__global__ __launch_bounds__(256) void glue_nopool(
    const float* __restrict__ att, const float* __restrict__ xres,
    const float* __restrict__ wo, const float* __restrict__ bo,
    const float* __restrict__ wq, const float* __restrict__ bq,
    float* __restrict__ xn, float* __restrict__ qn, float* __restrict__ kvn,
    int Nn)
{
  __shared__ __align__(16) float swoT[24 * 24];
  __shared__ float sbo[24];
  __shared__ __align__(16) float swqT[72 * 24];
  __shared__ float sbq[72];
  __shared__ __align__(16) float sy[64 * 28];
  const int tid = threadIdx.x;
  for (int i = tid; i < 576; i += 256) swoT[(i % 24) * 24 + i / 24] = wo[i];
  for (int i = tid; i < 1728; i += 256) swqT[(i % 72) * 24 + i / 72] = wq[i];
  if (tid < 24) sbo[tid] = bo[tid];
  if (tid < 72) sbq[tid] = bq[tid];
  __syncthreads();

  {  // phase 1
    const int lpx = tid >> 2, qt = tid & 3;
    const size_t spx = (size_t)blockIdx.x * 64 + lpx;
    float ar[24];
    const float4* ap = (const float4*)(att + spx * 24);
#pragma unroll
    for (int i = 0; i < 6; ++i) {
      const float4 f = ap[i];
      ar[4*i] = f.x; ar[4*i+1] = f.y; ar[4*i+2] = f.z; ar[4*i+3] = f.w;
    }
#pragma unroll
    for (int k = 0; k < 6; ++k) {
      const int c = qt * 6 + k;
      const float* wr = &swoT[c * 24];
      float acc = sbo[c] + xres[spx * 24 + c];
#pragma unroll
      for (int j = 0; j < 24; ++j) acc += ar[j] * wr[j];
      sy[lpx * 28 + c] = acc;
      xn[spx * 24 + c] = acc;
    }
  }
  __syncthreads();
  {  // phase 2
    const int lpx = tid >> 2, jg = tid & 3;
    const size_t gp = (size_t)blockIdx.x * 64 + lpx;
    const float* yr = &sy[lpx * 28];
    float xp[24];
#pragma unroll
    for (int c = 0; c < 24; ++c) xp[c] = yr[c];
#pragma unroll
    for (int jj = 0; jj < 18; ++jj) {
      const int j = jg * 18 + jj;
      const float* wr = &swqT[j * 24];
      float acc = sbq[j];
#pragma unroll
      for (int c = 0; c < 24; ++c) acc += xp[c] * wr[c];
      if (j < 24)      qn[((size_t)(j / 6) * Nn + gp) * 6 + j % 6] = acc * QS2;
      else if (j < 48) { const int u = j - 24; kvn[((size_t)(u / 6) * Nn + gp) * 12 + u % 6] = acc; }
      else             { const int u = j - 48; kvn[((size_t)(u / 6) * Nn + gp) * 12 + 6 + u % 6] = acc; }
    }
  }
}

// ============================================================================
// final_out: y = att@Wo+bo+res, stored transposed as dout[H][C][W].
// ============================================================================
__global__ __launch_bounds__(256) void final_out(
    const float* __restrict__ att, const float* __restrict__ xres,
    const float* __restrict__ wo, const float* __restrict__ bo,
    float* __restrict__ dout)
{
  __shared__ __align__(16) float swoT[24 * 24];
  __shared__ float sbo[24];
  const int tid = threadIdx.x;
  for (int i = tid; i < 576; i += 256) swoT[(i % 24) * 24 + i / 24] = wo[i];
  if (tid < 24) sbo[tid] = bo[tid];
  __syncthreads();
  const int lpx = tid >> 1, half = tid & 1;
  const size_t spx = (size_t)blockIdx.x * 128 + lpx;
  const int gh = (int)(spx / 88), gw = (int)(spx % 88);
  float ar[24];
  const float4* ap = (const float4*)(att + spx * 24);
#pragma unroll
  for (int i = 0; i < 6; ++i) {
    const float4 f = ap[i];
    ar[4*i] = f.x; ar[4*i+1] = f.y; ar[4*i+2] = f.z; ar[4*i+3] = f.w;
  }
  float res[12];
  const float4* rp = (const float4*)(xres + spx * 24 + half * 12);
#pragma unroll
  for (int i = 0; i < 3; ++i) {
    const float4 f = rp[i];
    res[4*i] = f.x; res[4*i+1] = f.y; res[4*i+2] = f.z; res[4*i+3] = f.w;
  }
#pragma unroll
  for (int k = 0; k < 12; ++k) {
    const int c = half * 12 + k;
    const float* wr = &swoT[c * 24];
    float acc = sbo[c] + res[k];
#pragma unroll
    for (int j = 0; j < 24; ++j) acc += ar[j] * wr[j];
    dout[((size_t)gh * 24 + c) * 88 + gw] = acc;
  }
}

// ============================================================================
extern "C" void kernel_launch(void* const* d_in, const int* in_sizes, int n_in,
                              void* d_out, int out_size, void* d_ws, size_t ws_size,
                              hipStream_t stream)
{
  const float* x      = (const float*)d_in[0];  // [64][352][24]
  const float* qkv_w  = (const float*)d_in[1];  // [4][24][72]
  const float* qkv_b  = (const float*)d_in[2];  // [4][72]
  const float* out_w  = (const float*)d_in[3];  // [4][24][24]
  const float* out_b  = (const float*)d_in[4];  // [4][24]
  float* out = (float*)d_out;                   // [64][24][88]
  float* ws = (float*)d_ws;

  const int N0 = 64 * 352, N1 = 64 * 176, N2 = 64 * 88;
  float* q_a  = ws;                        // [4][N][6]  (ping)
  float* kv_a = q_a + (size_t)N0 * 24;     // [4][N][12] (ping)
  float* q_b  = kv_a + (size_t)N0 * 48;    // (pong, sized N1)
  float* kv_b = q_b + (size_t)N1 * 24;
  float* att  = kv_b + (size_t)N1 * 48;    // [N][24] scratch (sized N0)
  float* x1   = att + (size_t)N0 * 24;
  float* x2   = x1 + (size_t)N1 * 24;
  float* x3   = x2 + (size_t)N2 * 24;      // total ~14 MB

  qkv_first<<<(N0 * 4) / 256, 256, 0, stream>>>(x, qkv_w, qkv_b, q_a, kv_a, N0);

  attn5_fused<<<dim3(44, 8), 256, 0, stream>>>(
      q_a, kv_a, x, out_w, out_b, qkv_w + 1728, qkv_b + 72,
      x1, q_b, kv_b, 64, 352, N1);

  attn5_fused<<<dim3(22, 8), 256, 0, stream>>>(
      q_b, kv_b, x1, out_w + 576, out_b + 24, qkv_w + 2 * 1728, qkv_b + 2 * 72,
      x2, q_a, kv_a, 64, 176, N2);

  attn25<<<dim3(11, 16, 4), 256, 0, stream>>>(q_a, kv_a, att);
  glue_nopool<<<88, 256, 0, stream>>>(att, x2, out_w + 2 * 576, out_b + 2 * 24,
                                      qkv_w + 3 * 1728, qkv_b + 3 * 72, x3, q_b, kv_b, N2);

  attn25<<<dim3(11, 16, 4), 256, 0, stream>>>(q_b, kv_b, att);
  final_out<<<44, 256, 0, stream>>>(att, x3, out_w + 3 * 576, out_b + 3 * 24, out);
}